// Round 4
// baseline (131.376 us; speedup 1.0000x reference)
//
#include <hip/hip_runtime.h>
#include <math.h>

#define BB 32
#define TT 1024
#define FF 128
#define DD 64
#define NCLS 11
constexpr float kEps = 1e-3f;
constexpr int M = BB * TT;  // 32768 rows

typedef __attribute__((ext_vector_type(8))) short short8v;
typedef __attribute__((ext_vector_type(4))) short short4v;
typedef __attribute__((ext_vector_type(4))) float float4v;

__device__ __forceinline__ short f2bf(float f) {
  union { float f; unsigned u; } v; v.f = f;
  return (short)((v.u + 0x7FFFu + ((v.u >> 16) & 1u)) >> 16);
}
__device__ __forceinline__ float bf2f(short s) {
  union { unsigned u; float f; } v; v.u = ((unsigned)(unsigned short)s) << 16;
  return v.f;
}

// ---------------------------------------------------------------- PE table
__global__ __launch_bounds__(256) void pe_kernel(float* __restrict__ pe) {
  int idx = blockIdx.x * 256 + threadIdx.x;          // 131072 total
  int t = idx >> 7, f = idx & 127;
  float div = expf(-logf(10000.0f) * (float)(f & ~1) / (float)FF);
  float ang = (float)t * div;
  pe[idx] = (f & 1) ? cosf(ang) : sinf(ang);
}

// ------------------------------------------- head constants + w0 transpose
__global__ __launch_bounds__(256) void prep_kernel(
    const float* __restrict__ w0,
    const float* __restrict__ bn_a_gamma, const float* __restrict__ bn_a_beta,
    const float* __restrict__ bn_a_mean, const float* __restrict__ bn_a_var,
    const float* __restrict__ bn1_gamma, const float* __restrict__ bn1_beta,
    const float* __restrict__ bn1_mean, const float* __restrict__ bn1_var,
    float* __restrict__ w0t, float* __restrict__ cA, float* __restrict__ cAo,
    float* __restrict__ c1s, float* __restrict__ c1o,
    float* __restrict__ c2s, float* __restrict__ c2o) {
  const int t = threadIdx.x;
  if (t < 64) {
    const float sA = bn_a_gamma[t] * rsqrtf(bn_a_var[t] + kEps);
    cA[t] = sA; cAo[t] = bn_a_beta[t] - bn_a_mean[t] * sA;
    const float s1 = bn1_gamma[t] * rsqrtf(bn1_var[t] + kEps);
    c1s[t] = s1; c1o[t] = bn1_beta[t] - bn1_mean[t] * s1;
    const float s2 = bn1_gamma[t + 64] * rsqrtf(bn1_var[t + 64] + kEps);
    c2s[t] = s2; c2o[t] = bn1_beta[t + 64] - bn1_mean[t + 64] * s2;
  }
  for (int i = t; i < 4096; i += 256) {
    const int e = i >> 6, k = i & 63;
    w0t[i] = w0[k * 64 + e];
  }
}

// --------------------------------- QKV + out2 projections (bf16 MFMA)
__global__ __launch_bounds__(256) void proj_kernel(
    const float* __restrict__ x, const float* __restrict__ pe,
    const float* __restrict__ wq, const float* __restrict__ wk,
    const float* __restrict__ wv, const float* __restrict__ w1,
    const float* __restrict__ b1,
    short* __restrict__ qo, short* __restrict__ ko,
    short* __restrict__ vt, short* __restrict__ o2) {
  __shared__ __align__(16) short xs[128 * 128];   // [row][k], chunk-swizzled
  __shared__ __align__(16) short wTs[64 * 128];   // [n][k], chunk-swizzled
  const int tid = threadIdx.x;
  const int lane = tid & 63;
  const int wv4 = tid >> 6;          // wave 0..3
  const int l15 = lane & 15;
  const int lg = lane >> 4;          // 0..3
  const int r0 = blockIdx.x * 128;
  const int y = blockIdx.y;
  const float* w = (y == 0) ? wq : (y == 1) ? wk : (y == 2) ? wv : w1;
  const bool addpe = (y < 3);

#pragma unroll
  for (int i = 0; i < 8; ++i) {
    int id = tid + i * 256;          // 0..2047
    int row = id >> 4, chunk = id & 15;
    const float* xp = &x[((size_t)(r0 + row)) * FF + chunk * 8];
    float4 a = *(const float4*)xp;
    float4 b = *(const float4*)(xp + 4);
    if (addpe) {
      const float* pp = &pe[((r0 & 1023) + row) * FF + chunk * 8];
      const float4 pa = *(const float4*)pp;
      const float4 pb = *(const float4*)(pp + 4);
      a.x += pa.x; a.y += pa.y; a.z += pa.z; a.w += pa.w;
      b.x += pb.x; b.y += pb.y; b.z += pb.z; b.w += pb.w;
    }
    short8v s8;
    s8[0] = f2bf(a.x); s8[1] = f2bf(a.y); s8[2] = f2bf(a.z); s8[3] = f2bf(a.w);
    s8[4] = f2bf(b.x); s8[5] = f2bf(b.y); s8[6] = f2bf(b.z); s8[7] = f2bf(b.w);
    *(short8v*)&xs[row * 128 + ((chunk ^ (row & 7)) << 3)] = s8;
  }

#pragma unroll
  for (int i = 0; i < 8; ++i) {
    int id = tid + i * 256;          // 0..2047
    int k = id >> 4, nq = id & 15;
    const float4 w4 = *(const float4*)&w[k * 64 + nq * 4];
    const float wvals[4] = {w4.x, w4.y, w4.z, w4.w};
#pragma unroll
    for (int j = 0; j < 4; ++j) {
      int n = nq * 4 + j;
      wTs[n * 128 + (((k >> 3) ^ (n & 7)) << 3) + (k & 7)] = f2bf(wvals[j]);
    }
  }
  __syncthreads();

  float4v acc[2][4];
#pragma unroll
  for (int rt = 0; rt < 2; ++rt)
#pragma unroll
    for (int dt = 0; dt < 4; ++dt) acc[rt][dt] = (float4v)0.0f;

  const bool natural = (y == 2);
#pragma unroll
  for (int kt = 0; kt < 4; ++kt) {
    const int chunk = kt * 4 + lg;
    short8v xa[2], wa[4];
#pragma unroll
    for (int rt = 0; rt < 2; ++rt) {
      const int row = wv4 * 32 + rt * 16 + l15;
      xa[rt] = *(const short8v*)&xs[row * 128 + ((chunk ^ (row & 7)) << 3)];
    }
#pragma unroll
    for (int dt = 0; dt < 4; ++dt) {
      const int n = dt * 16 + l15;
      wa[dt] = *(const short8v*)&wTs[n * 128 + ((chunk ^ (n & 7)) << 3)];
    }
#pragma unroll
    for (int rt = 0; rt < 2; ++rt)
#pragma unroll
      for (int dt = 0; dt < 4; ++dt)
        acc[rt][dt] = natural
            ? __builtin_amdgcn_mfma_f32_16x16x32_bf16(xa[rt], wa[dt], acc[rt][dt], 0, 0, 0)
            : __builtin_amdgcn_mfma_f32_16x16x32_bf16(wa[dt], xa[rt], acc[rt][dt], 0, 0, 0);
  }

  if (natural) {
    const int bq = r0 >> 10;
    const int tb = (r0 & 1023) + wv4 * 32;
#pragma unroll
    for (int rt = 0; rt < 2; ++rt) {
#pragma unroll
      for (int dt = 0; dt < 4; ++dt) {
        const int d = dt * 16 + l15;
        const int t0 = tb + rt * 16 + lg * 4;
        short4v s;
#pragma unroll
        for (int r = 0; r < 4; ++r) s[r] = f2bf(acc[rt][dt][r]);
        *(short4v*)&vt[((size_t)(bq * DD + d)) * TT + t0] = s;
      }
    }
  } else {
    short* dst = (y == 0) ? qo : (y == 1) ? ko : o2;
#pragma unroll
    for (int rt = 0; rt < 2; ++rt) {
      const int row = r0 + wv4 * 32 + rt * 16 + l15;
#pragma unroll
      for (int dt = 0; dt < 4; ++dt) {
        const int d0 = dt * 16 + lg * 4;
        float v0 = acc[rt][dt][0], v1 = acc[rt][dt][1];
        float v2 = acc[rt][dt][2], v3 = acc[rt][dt][3];
        if (y == 3) {
          const float4 bv = *(const float4*)&b1[d0];
          v0 = fmaxf(v0 + bv.x, 0.f); v1 = fmaxf(v1 + bv.y, 0.f);
          v2 = fmaxf(v2 + bv.z, 0.f); v3 = fmaxf(v3 + bv.w, 0.f);
        }
        short4v s;
        s[0] = f2bf(v0); s[1] = f2bf(v1); s[2] = f2bf(v2); s[3] = f2bf(v3);
        *(short4v*)&dst[(size_t)row * DD + d0] = s;
      }
    }
  }
}

// ------------------------------------------------ MFMA flash attention (bf16)
// grid: (T/64, B, S). 4 waves/block, wave = 16 q-rows. KVBLK=64.
__global__ __launch_bounds__(256) void attn_kernel(
    const short* __restrict__ qg, const short* __restrict__ kg,
    const short* __restrict__ vtg, short* __restrict__ po,
    float* __restrict__ pl, int ktiles) {
  __shared__ __align__(16) short Ks[64 * 64];      // [kv][d]
  __shared__ __align__(16) short Vs[64 * 64];      // [d][kv]
  __shared__ __align__(16) short Ps[4 * 16 * 64];  // per-wave [i][j]
  const int tid = threadIdx.x;
  const int lane = tid & 63;
  const int wv = tid >> 6;
  const int b = blockIdx.y;
  const int sidx = blockIdx.z;
  const int qx = blockIdx.x;
  const int l15 = lane & 15;
  const int lg = lane >> 4;          // 0..3
  const int qbase = qx * 64 + wv * 16;

  short8v qf[2];
#pragma unroll
  for (int dt = 0; dt < 2; ++dt) {
    const size_t off = ((size_t)(b * TT + qbase + l15)) * DD + dt * 32 + lg * 8;
    qf[dt] = *(const short8v*)&qg[off];
  }
  float4v oacc[4];
#pragma unroll
  for (int dt = 0; dt < 4; ++dt) oacc[dt] = (float4v)0.0f;
  float lacc[4] = {0.f, 0.f, 0.f, 0.f};

  const int kt0 = sidx * ktiles;
  const int pbase = wv * 1024;
  for (int kt = kt0; kt < kt0 + ktiles; ++kt) {
    __syncthreads();
#pragma unroll
    for (int p = 0; p < 2; ++p) {
      int idx = tid + p * 256;       // 0..511
      int row = idx >> 3, c8 = (idx & 7) * 8;
      int sw = c8 ^ ((row & 7) << 3);
      int4 kv = *(const int4*)&kg[((size_t)(b * TT + kt * 64 + row)) * DD + c8];
      *(int4*)&Ks[row * 64 + sw] = kv;
      int4 vv = *(const int4*)&vtg[((size_t)(b * DD + row)) * TT + kt * 64 + c8];
      *(int4*)&Vs[row * 64 + sw] = vv;
    }
    __syncthreads();

#pragma unroll
    for (int jt = 0; jt < 4; ++jt) {
      float4v s = {0.f, 0.f, 0.f, 0.f};
      const int j = jt * 16 + l15;
#pragma unroll
      for (int dt = 0; dt < 2; ++dt) {
        const int d0 = dt * 32 + lg * 8;
        short8v kf = *(const short8v*)&Ks[j * 64 + (d0 ^ ((j & 7) << 3))];
        s = __builtin_amdgcn_mfma_f32_16x16x32_bf16(qf[dt], kf, s, 0, 0, 0);
      }
#pragma unroll
      for (int r = 0; r < 4; ++r) {
        float pv = __expf(s[r] * 0.125f);
        lacc[r] += pv;
        const int i = lg * 4 + r;
        Ps[pbase + i * 64 + (j ^ ((i & 7) << 3))] = f2bf(pv);
      }
    }

    short8v pf[2];
#pragma unroll
    for (int jc = 0; jc < 2; ++jc) {
      const int j0 = jc * 32 + lg * 8;
      pf[jc] = *(const short8v*)&Ps[pbase + l15 * 64 + (j0 ^ ((l15 & 7) << 3))];
    }
#pragma unroll
    for (int dt = 0; dt < 4; ++dt) {
      const int d = dt * 16 + l15;
#pragma unroll
      for (int jc = 0; jc < 2; ++jc) {
        const int j0 = jc * 32 + lg * 8;
        short8v vf = *(const short8v*)&Vs[d * 64 + (j0 ^ ((d & 7) << 3))];
        oacc[dt] = __builtin_amdgcn_mfma_f32_16x16x32_bf16(pf[jc], vf, oacc[dt], 0, 0, 0);
      }
    }
  }

#pragma unroll
  for (int off = 1; off < 16; off <<= 1) {
#pragma unroll
    for (int r = 0; r < 4; ++r) lacc[r] += __shfl_xor(lacc[r], off);
  }

  const size_t growb = (size_t)b * TT + qbase + lg * 4;
#pragma unroll
  for (int r = 0; r < 4; ++r) {
    const size_t obase = ((size_t)sidx * M + growb + r) * DD;
#pragma unroll
    for (int dt = 0; dt < 4; ++dt)
      po[obase + dt * 16 + l15] = f2bf(oacc[dt][r]);
  }
#pragma unroll
  for (int r = 0; r < 4; ++r)
    if (l15 == r) pl[(size_t)sidx * M + growb + r] = lacc[r];
}

// ----------------- fused combine + bn_a -> out1 -> bn1 -> logits -> softmax
// thread = one row; barrier-free, LDS-free (weights via wave-uniform s_loads)
__global__ __launch_bounds__(256) void head_kernel(
    const short* __restrict__ po, const float* __restrict__ pl,
    const short* __restrict__ o2m,
    const float* __restrict__ w0t, const float* __restrict__ b0,
    const float* __restrict__ cA, const float* __restrict__ cAo,
    const float* __restrict__ c1s, const float* __restrict__ c1o,
    const float* __restrict__ c2s, const float* __restrict__ c2o,
    const float* __restrict__ wd, const float* __restrict__ bd,
    float* __restrict__ out, int S) {
  const int row = blockIdx.x * 256 + threadIdx.x;

  float l = 0.f;
  for (int s = 0; s < S; ++s) l += pl[(size_t)s * M + row];

  float xa[64];
#pragma unroll
  for (int d = 0; d < 64; ++d) xa[d] = 0.f;
  for (int s = 0; s < S; ++s) {
    const short8v* p = (const short8v*)&po[((size_t)s * M + row) * DD];
#pragma unroll
    for (int i = 0; i < 8; ++i) {
      const short8v v = p[i];
#pragma unroll
      for (int j = 0; j < 8; ++j) xa[i * 8 + j] += bf2f(v[j]);
    }
  }
  const float inv = 1.f / l;
#pragma unroll
  for (int d = 0; d < 64; ++d) xa[d] = xa[d] * inv * cA[d] + cAo[d];

  float lacc[NCLS];
#pragma unroll
  for (int c = 0; c < NCLS; ++c) lacc[c] = bd[c];

  // h1 half: out1[e] = relu(xa . w0t[e]) folded into bn1 consts
  for (int e = 0; e < 64; e += 2) {
    float a0 = b0[e], a1 = b0[e + 1];
    const float* wr0 = &w0t[e * 64];
    const float* wr1 = wr0 + 64;
#pragma unroll
    for (int k = 0; k < 64; ++k) {
      a0 += xa[k] * wr0[k];
      a1 += xa[k] * wr1[k];
    }
    const float h0 = fmaxf(a0, 0.f) * c1s[e] + c1o[e];
    const float h1 = fmaxf(a1, 0.f) * c1s[e + 1] + c1o[e + 1];
    const float* wde = &wd[e * NCLS];
#pragma unroll
    for (int c = 0; c < NCLS; ++c) lacc[c] += h0 * wde[c] + h1 * wde[NCLS + c];
  }

  // h2 half from o2 (already relu'd in proj)
  const short8v* o2p = (const short8v*)&o2m[(size_t)row * DD];
#pragma unroll
  for (int i = 0; i < 8; ++i) {
    const short8v v = o2p[i];
#pragma unroll
    for (int j = 0; j < 8; ++j) {
      const int e = i * 8 + j;
      const float h2 = bf2f(v[j]) * c2s[e] + c2o[e];
      const float* wde = &wd[(64 + e) * NCLS];
#pragma unroll
      for (int c = 0; c < NCLS; ++c) lacc[c] += h2 * wde[c];
    }
  }

  // softmax over 11
  float mx = lacc[0];
#pragma unroll
  for (int c = 1; c < NCLS; ++c) mx = fmaxf(mx, lacc[c]);
  float sum = 0.f;
#pragma unroll
  for (int c = 0; c < NCLS; ++c) { lacc[c] = __expf(lacc[c] - mx); sum += lacc[c]; }
  const float isum = 1.f / sum;
#pragma unroll
  for (int c = 0; c < NCLS; ++c) out[(size_t)row * NCLS + c] = lacc[c] * isum;
}

// -----------------------------------------------------------------------
extern "C" void kernel_launch(void* const* d_in, const int* in_sizes, int n_in,
                              void* d_out, int out_size, void* d_ws, size_t ws_size,
                              hipStream_t stream) {
  (void)in_sizes; (void)n_in; (void)out_size;
  const float* x  = (const float*)d_in[0];
  const float* wq = (const float*)d_in[1];
  const float* wk = (const float*)d_in[2];
  const float* wv = (const float*)d_in[3];
  const float* bn_a_gamma = (const float*)d_in[4];
  const float* bn_a_beta  = (const float*)d_in[5];
  const float* bn_a_mean  = (const float*)d_in[6];
  const float* bn_a_var   = (const float*)d_in[7];
  const float* w0 = (const float*)d_in[8];
  const float* b0 = (const float*)d_in[9];
  const float* w1 = (const float*)d_in[10];
  const float* b1 = (const float*)d_in[11];
  const float* bn1_gamma = (const float*)d_in[12];
  const float* bn1_beta  = (const float*)d_in[13];
  const float* bn1_mean  = (const float*)d_in[14];
  const float* bn1_var   = (const float*)d_in[15];
  const float* wd = (const float*)d_in[16];
  const float* bd = (const float*)d_in[17];
  float* out = (float*)d_out;

  char* cur = (char*)d_ws;
  float* pe = (float*)cur; cur += (size_t)TT * FF * 4;
  short* q  = (short*)cur; cur += (size_t)M * DD * 2;
  short* k  = (short*)cur; cur += (size_t)M * DD * 2;
  short* vt = (short*)cur; cur += (size_t)M * DD * 2;
  short* o2 = (short*)cur; cur += (size_t)M * DD * 2;
  float* w0t = (float*)cur; cur += 4096 * 4;
  float* cA  = (float*)cur; cur += 64 * 4;
  float* cAo = (float*)cur; cur += 64 * 4;
  float* c1s = (float*)cur; cur += 64 * 4;
  float* c1o = (float*)cur; cur += 64 * 4;
  float* c2s = (float*)cur; cur += 64 * 4;
  float* c2o = (float*)cur; cur += 64 * 4;
  const size_t used = (size_t)(cur - (char*)d_ws);
  int S = 4;
  while (S > 1 && used + (size_t)S * ((size_t)M * DD * 2 + M * 4) > ws_size) S >>= 1;
  short* po = (short*)cur;
  float* pl = (float*)(po + (size_t)S * M * DD);

  pe_kernel<<<dim3(TT * FF / 256), dim3(256), 0, stream>>>(pe);
  prep_kernel<<<dim3(1), dim3(256), 0, stream>>>(
      w0, bn_a_gamma, bn_a_beta, bn_a_mean, bn_a_var,
      bn1_gamma, bn1_beta, bn1_mean, bn1_var,
      w0t, cA, cAo, c1s, c1o, c2s, c2o);
  proj_kernel<<<dim3(M / 128, 4), dim3(256), 0, stream>>>(
      x, pe, wq, wk, wv, w1, b1, q, k, vt, o2);
  attn_kernel<<<dim3(TT / 64, BB, S), dim3(256), 0, stream>>>(
      q, k, vt, po, pl, 16 / S);
  head_kernel<<<dim3(M / 256), dim3(256), 0, stream>>>(
      po, pl, o2, w0t, b0, cA, cAo, c1s, c1o, c2s, c2o, wd, bd, out, S);
}

// Round 5
// 73.686 us; speedup vs baseline: 1.7829x; 1.7829x over previous
//
#include <hip/hip_runtime.h>
#include <math.h>

#define BB 32
#define TT 1024
#define FF 128
#define DD 64
#define NCLS 11
constexpr float kEps = 1e-3f;
constexpr int M = BB * TT;  // 32768 rows

typedef __attribute__((ext_vector_type(8))) short short8v;
typedef __attribute__((ext_vector_type(4))) short short4v;
typedef __attribute__((ext_vector_type(4))) float float4v;

__device__ __forceinline__ short f2bf(float f) {
  union { float f; unsigned u; } v; v.f = f;
  return (short)((v.u + 0x7FFFu + ((v.u >> 16) & 1u)) >> 16);
}
__device__ __forceinline__ float bf2f(short s) {
  union { unsigned u; float f; } v; v.u = ((unsigned)(unsigned short)s) << 16;
  return v.f;
}

// ---------------------------------------------------------------- PE table
__global__ __launch_bounds__(256) void pe_kernel(float* __restrict__ pe) {
  int idx = blockIdx.x * 256 + threadIdx.x;          // 131072 total
  int t = idx >> 7, f = idx & 127;
  float div = expf(-logf(10000.0f) * (float)(f & ~1) / (float)FF);
  float ang = (float)t * div;
  pe[idx] = (f & 1) ? cosf(ang) : sinf(ang);
}

// ---------------- prep: fold BN/bias into head weights (bf16) ----------
// w0pT[e][k] = cA[k]*w0[k][e];  b0p[e] = b0[e] + sum_k cAo[k]*w0[k][e]
// wdpT[c][e] = wd[e][c] * (e<64 ? c1s[e] : c2s[e-64])   (c padded to 16)
// bdp[c] = bd[c] + sum_e c1o[e]*wd[e][c] + sum_e c2o[e]*wd[64+e][c]
__global__ __launch_bounds__(256) void prep_kernel(
    const float* __restrict__ w0, const float* __restrict__ b0,
    const float* __restrict__ bn_a_gamma, const float* __restrict__ bn_a_beta,
    const float* __restrict__ bn_a_mean, const float* __restrict__ bn_a_var,
    const float* __restrict__ bn1_gamma, const float* __restrict__ bn1_beta,
    const float* __restrict__ bn1_mean, const float* __restrict__ bn1_var,
    const float* __restrict__ wd, const float* __restrict__ bd,
    short* __restrict__ w0pT, float* __restrict__ b0p,
    short* __restrict__ wdpT, float* __restrict__ bdp) {
  __shared__ float cA[64], cAo[64], c1s[64], c1o[64], c2s[64], c2o[64];
  const int t = threadIdx.x;
  if (t < 64) {
    const float sA = bn_a_gamma[t] * rsqrtf(bn_a_var[t] + kEps);
    cA[t] = sA; cAo[t] = bn_a_beta[t] - bn_a_mean[t] * sA;
    const float s1 = bn1_gamma[t] * rsqrtf(bn1_var[t] + kEps);
    c1s[t] = s1; c1o[t] = bn1_beta[t] - bn1_mean[t] * s1;
    const float s2 = bn1_gamma[t + 64] * rsqrtf(bn1_var[t + 64] + kEps);
    c2s[t] = s2; c2o[t] = bn1_beta[t + 64] - bn1_mean[t + 64] * s2;
  }
  __syncthreads();
  for (int i = t; i < 4096; i += 256) {
    const int e = i >> 6, k = i & 63;
    w0pT[i] = f2bf(cA[k] * w0[k * 64 + e]);
  }
  if (t < 64) {
    float s = b0[t];
    for (int k = 0; k < 64; ++k) s += cAo[k] * w0[k * 64 + t];
    b0p[t] = s;
  }
  for (int i = t; i < 2048; i += 256) {
    const int c = i >> 7, e = i & 127;
    float v = 0.f;
    if (c < NCLS) v = wd[e * NCLS + c] * (e < 64 ? c1s[e] : c2s[e - 64]);
    wdpT[i] = f2bf(v);
  }
  if (t < 16) {
    float s = 0.f;
    if (t < NCLS) {
      s = bd[t];
      for (int e = 0; e < 64; ++e) s += c1o[e] * wd[e * NCLS + t];
      for (int e = 0; e < 64; ++e) s += c2o[e] * wd[(64 + e) * NCLS + t];
    }
    bdp[t] = s;
  }
}

// --------------------------------- QKV + out2 projections (bf16 MFMA)
__global__ __launch_bounds__(256) void proj_kernel(
    const float* __restrict__ x, const float* __restrict__ pe,
    const float* __restrict__ wq, const float* __restrict__ wk,
    const float* __restrict__ wv, const float* __restrict__ w1,
    const float* __restrict__ b1,
    short* __restrict__ qo, short* __restrict__ ko,
    short* __restrict__ vt, short* __restrict__ o2) {
  __shared__ __align__(16) short xs[128 * 128];   // [row][k], chunk-swizzled
  __shared__ __align__(16) short wTs[64 * 128];   // [n][k], chunk-swizzled
  const int tid = threadIdx.x;
  const int lane = tid & 63;
  const int wv4 = tid >> 6;          // wave 0..3
  const int l15 = lane & 15;
  const int lg = lane >> 4;          // 0..3
  const int r0 = blockIdx.x * 128;
  const int y = blockIdx.y;
  const float* w = (y == 0) ? wq : (y == 1) ? wk : (y == 2) ? wv : w1;
  const bool addpe = (y < 3);

#pragma unroll
  for (int i = 0; i < 8; ++i) {
    int id = tid + i * 256;          // 0..2047
    int row = id >> 4, chunk = id & 15;
    const float* xp = &x[((size_t)(r0 + row)) * FF + chunk * 8];
    float4 a = *(const float4*)xp;
    float4 b = *(const float4*)(xp + 4);
    if (addpe) {
      const float* pp = &pe[((r0 & 1023) + row) * FF + chunk * 8];
      const float4 pa = *(const float4*)pp;
      const float4 pb = *(const float4*)(pp + 4);
      a.x += pa.x; a.y += pa.y; a.z += pa.z; a.w += pa.w;
      b.x += pb.x; b.y += pb.y; b.z += pb.z; b.w += pb.w;
    }
    short8v s8;
    s8[0] = f2bf(a.x); s8[1] = f2bf(a.y); s8[2] = f2bf(a.z); s8[3] = f2bf(a.w);
    s8[4] = f2bf(b.x); s8[5] = f2bf(b.y); s8[6] = f2bf(b.z); s8[7] = f2bf(b.w);
    *(short8v*)&xs[row * 128 + ((chunk ^ (row & 7)) << 3)] = s8;
  }

#pragma unroll
  for (int i = 0; i < 8; ++i) {
    int id = tid + i * 256;          // 0..2047
    int k = id >> 4, nq = id & 15;
    const float4 w4 = *(const float4*)&w[k * 64 + nq * 4];
    const float wvals[4] = {w4.x, w4.y, w4.z, w4.w};
#pragma unroll
    for (int j = 0; j < 4; ++j) {
      int n = nq * 4 + j;
      wTs[n * 128 + (((k >> 3) ^ (n & 7)) << 3) + (k & 7)] = f2bf(wvals[j]);
    }
  }
  __syncthreads();

  float4v acc[2][4];
#pragma unroll
  for (int rt = 0; rt < 2; ++rt)
#pragma unroll
    for (int dt = 0; dt < 4; ++dt) acc[rt][dt] = (float4v)0.0f;

  const bool natural = (y == 2);
#pragma unroll
  for (int kt = 0; kt < 4; ++kt) {
    const int chunk = kt * 4 + lg;
    short8v xa[2], wa[4];
#pragma unroll
    for (int rt = 0; rt < 2; ++rt) {
      const int row = wv4 * 32 + rt * 16 + l15;
      xa[rt] = *(const short8v*)&xs[row * 128 + ((chunk ^ (row & 7)) << 3)];
    }
#pragma unroll
    for (int dt = 0; dt < 4; ++dt) {
      const int n = dt * 16 + l15;
      wa[dt] = *(const short8v*)&wTs[n * 128 + ((chunk ^ (n & 7)) << 3)];
    }
#pragma unroll
    for (int rt = 0; rt < 2; ++rt)
#pragma unroll
      for (int dt = 0; dt < 4; ++dt)
        acc[rt][dt] = natural
            ? __builtin_amdgcn_mfma_f32_16x16x32_bf16(xa[rt], wa[dt], acc[rt][dt], 0, 0, 0)
            : __builtin_amdgcn_mfma_f32_16x16x32_bf16(wa[dt], xa[rt], acc[rt][dt], 0, 0, 0);
  }

  if (natural) {
    const int bq = r0 >> 10;
    const int tb = (r0 & 1023) + wv4 * 32;
#pragma unroll
    for (int rt = 0; rt < 2; ++rt) {
#pragma unroll
      for (int dt = 0; dt < 4; ++dt) {
        const int d = dt * 16 + l15;
        const int t0 = tb + rt * 16 + lg * 4;
        short4v s;
#pragma unroll
        for (int r = 0; r < 4; ++r) s[r] = f2bf(acc[rt][dt][r]);
        *(short4v*)&vt[((size_t)(bq * DD + d)) * TT + t0] = s;
      }
    }
  } else {
    short* dst = (y == 0) ? qo : (y == 1) ? ko : o2;
#pragma unroll
    for (int rt = 0; rt < 2; ++rt) {
      const int row = r0 + wv4 * 32 + rt * 16 + l15;
#pragma unroll
      for (int dt = 0; dt < 4; ++dt) {
        const int d0 = dt * 16 + lg * 4;
        float v0 = acc[rt][dt][0], v1 = acc[rt][dt][1];
        float v2 = acc[rt][dt][2], v3 = acc[rt][dt][3];
        if (y == 3) {
          const float4 bv = *(const float4*)&b1[d0];
          v0 = fmaxf(v0 + bv.x, 0.f); v1 = fmaxf(v1 + bv.y, 0.f);
          v2 = fmaxf(v2 + bv.z, 0.f); v3 = fmaxf(v3 + bv.w, 0.f);
        }
        short4v s;
        s[0] = f2bf(v0); s[1] = f2bf(v1); s[2] = f2bf(v2); s[3] = f2bf(v3);
        *(short4v*)&dst[(size_t)row * DD + d0] = s;
      }
    }
  }
}

// ------------------------------------------------ MFMA flash attention (bf16)
// grid: (T/64, B, S). 4 waves/block, wave = 16 q-rows. KVBLK=64.
__global__ __launch_bounds__(256) void attn_kernel(
    const short* __restrict__ qg, const short* __restrict__ kg,
    const short* __restrict__ vtg, short* __restrict__ po,
    float* __restrict__ pl, int ktiles) {
  __shared__ __align__(16) short Ks[64 * 64];      // [kv][d]
  __shared__ __align__(16) short Vs[64 * 64];      // [d][kv]
  __shared__ __align__(16) short Ps[4 * 16 * 64];  // per-wave [i][j]
  const int tid = threadIdx.x;
  const int lane = tid & 63;
  const int wv = tid >> 6;
  const int b = blockIdx.y;
  const int sidx = blockIdx.z;
  const int qx = blockIdx.x;
  const int l15 = lane & 15;
  const int lg = lane >> 4;          // 0..3
  const int qbase = qx * 64 + wv * 16;

  short8v qf[2];
#pragma unroll
  for (int dt = 0; dt < 2; ++dt) {
    const size_t off = ((size_t)(b * TT + qbase + l15)) * DD + dt * 32 + lg * 8;
    qf[dt] = *(const short8v*)&qg[off];
  }
  float4v oacc[4];
#pragma unroll
  for (int dt = 0; dt < 4; ++dt) oacc[dt] = (float4v)0.0f;
  float lacc[4] = {0.f, 0.f, 0.f, 0.f};

  const int kt0 = sidx * ktiles;
  const int pbase = wv * 1024;
  for (int kt = kt0; kt < kt0 + ktiles; ++kt) {
    __syncthreads();
#pragma unroll
    for (int p = 0; p < 2; ++p) {
      int idx = tid + p * 256;       // 0..511
      int row = idx >> 3, c8 = (idx & 7) * 8;
      int sw = c8 ^ ((row & 7) << 3);
      int4 kv = *(const int4*)&kg[((size_t)(b * TT + kt * 64 + row)) * DD + c8];
      *(int4*)&Ks[row * 64 + sw] = kv;
      int4 vv = *(const int4*)&vtg[((size_t)(b * DD + row)) * TT + kt * 64 + c8];
      *(int4*)&Vs[row * 64 + sw] = vv;
    }
    __syncthreads();

#pragma unroll
    for (int jt = 0; jt < 4; ++jt) {
      float4v s = {0.f, 0.f, 0.f, 0.f};
      const int j = jt * 16 + l15;
#pragma unroll
      for (int dt = 0; dt < 2; ++dt) {
        const int d0 = dt * 32 + lg * 8;
        short8v kf = *(const short8v*)&Ks[j * 64 + (d0 ^ ((j & 7) << 3))];
        s = __builtin_amdgcn_mfma_f32_16x16x32_bf16(qf[dt], kf, s, 0, 0, 0);
      }
#pragma unroll
      for (int r = 0; r < 4; ++r) {
        float pv = __expf(s[r] * 0.125f);
        lacc[r] += pv;
        const int i = lg * 4 + r;
        Ps[pbase + i * 64 + (j ^ ((i & 7) << 3))] = f2bf(pv);
      }
    }

    short8v pf[2];
#pragma unroll
    for (int jc = 0; jc < 2; ++jc) {
      const int j0 = jc * 32 + lg * 8;
      pf[jc] = *(const short8v*)&Ps[pbase + l15 * 64 + (j0 ^ ((l15 & 7) << 3))];
    }
#pragma unroll
    for (int dt = 0; dt < 4; ++dt) {
      const int d = dt * 16 + l15;
#pragma unroll
      for (int jc = 0; jc < 2; ++jc) {
        const int j0 = jc * 32 + lg * 8;
        short8v vf = *(const short8v*)&Vs[d * 64 + (j0 ^ ((d & 7) << 3))];
        oacc[dt] = __builtin_amdgcn_mfma_f32_16x16x32_bf16(pf[jc], vf, oacc[dt], 0, 0, 0);
      }
    }
  }

#pragma unroll
  for (int off = 1; off < 16; off <<= 1) {
#pragma unroll
    for (int r = 0; r < 4; ++r) lacc[r] += __shfl_xor(lacc[r], off);
  }

  const size_t growb = (size_t)b * TT + qbase + lg * 4;
#pragma unroll
  for (int r = 0; r < 4; ++r) {
    const size_t obase = ((size_t)sidx * M + growb + r) * DD;
#pragma unroll
    for (int dt = 0; dt < 4; ++dt)
      po[obase + dt * 16 + l15] = f2bf(oacc[dt][r]);
  }
#pragma unroll
  for (int r = 0; r < 4; ++r)
    if (l15 == r) pl[(size_t)sidx * M + growb + r] = lacc[r];
}

// ---------------- fused combine + head via MFMA (folded BN/bias) -------
// grid: M/64 blocks, 4 waves; wave = 16 rows. Barrier-free (wave-private LDS).
__global__ __launch_bounds__(256) void head_kernel(
    const short* __restrict__ po, const float* __restrict__ pl,
    const short* __restrict__ o2m,
    const short* __restrict__ w0pT, const float* __restrict__ b0p,
    const short* __restrict__ wdpT, const float* __restrict__ bdp,
    float* __restrict__ out, int S) {
  __shared__ __align__(16) short hs[4][16 * 64];   // per-wave, chunk-swizzled
  const int tid = threadIdx.x;
  const int lane = tid & 63;
  const int wv = tid >> 6;
  const int l15 = lane & 15;
  const int lg = lane >> 4;
  const int r0w = blockIdx.x * 64 + wv * 16;       // wave's first row
  const int rowA = r0w + l15;

  // row-sum normalizer
  float l = 0.f;
  for (int s = 0; s < S; ++s) l += pl[(size_t)s * M + rowA];
  const float inv = 1.f / l;

  // A-frags: sum po partials over S (fp32), convert to bf16
  short8v af[2];
#pragma unroll
  for (int dt = 0; dt < 2; ++dt) {
    float sum[8] = {0.f, 0.f, 0.f, 0.f, 0.f, 0.f, 0.f, 0.f};
    for (int s = 0; s < S; ++s) {
      const short8v v = *(const short8v*)&po[((size_t)s * M + rowA) * DD + dt * 32 + lg * 8];
#pragma unroll
      for (int j = 0; j < 8; ++j) sum[j] += bf2f(v[j]);
    }
#pragma unroll
    for (int j = 0; j < 8; ++j) af[dt][j] = f2bf(sum[j]);
  }

  // out1 = inv*(s . w0') + b0'   (MFMA)
  float4v acc1[4];
#pragma unroll
  for (int et = 0; et < 4; ++et) acc1[et] = (float4v)0.0f;
#pragma unroll
  for (int et = 0; et < 4; ++et)
#pragma unroll
    for (int dt = 0; dt < 2; ++dt) {
      const short8v wb = *(const short8v*)&w0pT[(et * 16 + l15) * 64 + dt * 32 + lg * 8];
      acc1[et] = __builtin_amdgcn_mfma_f32_16x16x32_bf16(af[dt], wb, acc1[et], 0, 0, 0);
    }

  float b0v[4];
#pragma unroll
  for (int et = 0; et < 4; ++et) b0v[et] = b0p[et * 16 + l15];

  // scale + bias + relu -> bf16 -> wave-private LDS (A-layout for logits GEMM)
#pragma unroll
  for (int r = 0; r < 4; ++r) {
    const float invm = __shfl(inv, lg * 4 + r);
    const int m = lg * 4 + r;
#pragma unroll
    for (int et = 0; et < 4; ++et) {
      const float v = fmaxf(acc1[et][r] * invm + b0v[et], 0.f);
      const int chunk = ((et * 2 + (l15 >> 3)) ^ (m & 7));
      hs[wv][m * 64 + chunk * 8 + (l15 & 7)] = f2bf(v);
    }
  }

  // logits = h1 . wd1' + o2 . wd2' + bd'   (MFMA; c = l15 col, padded to 16)
  float4v accL = (float4v)0.0f;
#pragma unroll
  for (int dt = 0; dt < 2; ++dt) {
    const int chunk = ((dt * 4 + lg) ^ (l15 & 7));
    const short8v ha = *(const short8v*)&hs[wv][l15 * 64 + chunk * 8];
    const short8v wb = *(const short8v*)&wdpT[l15 * 128 + dt * 32 + lg * 8];
    accL = __builtin_amdgcn_mfma_f32_16x16x32_bf16(ha, wb, accL, 0, 0, 0);
  }
#pragma unroll
  for (int dt = 0; dt < 2; ++dt) {
    const short8v ha = *(const short8v*)&o2m[(size_t)rowA * DD + dt * 32 + lg * 8];
    const short8v wb = *(const short8v*)&wdpT[l15 * 128 + 64 + dt * 32 + lg * 8];
    accL = __builtin_amdgcn_mfma_f32_16x16x32_bf16(ha, wb, accL, 0, 0, 0);
  }

  const float bdv = bdp[l15];
#pragma unroll
  for (int r = 0; r < 4; ++r) {
    const float lv = (l15 < NCLS) ? (accL[r] + bdv) : -1e30f;
    float mx = lv;
#pragma unroll
    for (int off = 1; off < 16; off <<= 1) mx = fmaxf(mx, __shfl_xor(mx, off));
    const float ex = (l15 < NCLS) ? __expf(lv - mx) : 0.f;
    float sm = ex;
#pragma unroll
    for (int off = 1; off < 16; off <<= 1) sm += __shfl_xor(sm, off);
    if (l15 < NCLS)
      out[(size_t)(r0w + lg * 4 + r) * NCLS + l15] = ex / sm;
  }
}

// -----------------------------------------------------------------------
extern "C" void kernel_launch(void* const* d_in, const int* in_sizes, int n_in,
                              void* d_out, int out_size, void* d_ws, size_t ws_size,
                              hipStream_t stream) {
  (void)in_sizes; (void)n_in; (void)out_size;
  const float* x  = (const float*)d_in[0];
  const float* wq = (const float*)d_in[1];
  const float* wk = (const float*)d_in[2];
  const float* wv = (const float*)d_in[3];
  const float* bn_a_gamma = (const float*)d_in[4];
  const float* bn_a_beta  = (const float*)d_in[5];
  const float* bn_a_mean  = (const float*)d_in[6];
  const float* bn_a_var   = (const float*)d_in[7];
  const float* w0 = (const float*)d_in[8];
  const float* b0 = (const float*)d_in[9];
  const float* w1 = (const float*)d_in[10];
  const float* b1 = (const float*)d_in[11];
  const float* bn1_gamma = (const float*)d_in[12];
  const float* bn1_beta  = (const float*)d_in[13];
  const float* bn1_mean  = (const float*)d_in[14];
  const float* bn1_var   = (const float*)d_in[15];
  const float* wd = (const float*)d_in[16];
  const float* bd = (const float*)d_in[17];
  float* out = (float*)d_out;

  char* cur = (char*)d_ws;
  float* pe = (float*)cur; cur += (size_t)TT * FF * 4;
  short* q  = (short*)cur; cur += (size_t)M * DD * 2;
  short* k  = (short*)cur; cur += (size_t)M * DD * 2;
  short* vt = (short*)cur; cur += (size_t)M * DD * 2;
  short* o2 = (short*)cur; cur += (size_t)M * DD * 2;
  short* w0pT = (short*)cur; cur += 4096 * 2;
  short* wdpT = (short*)cur; cur += 2048 * 2;
  float* b0p  = (float*)cur; cur += 64 * 4;
  float* bdp  = (float*)cur; cur += 16 * 4;
  const size_t used = (size_t)(cur - (char*)d_ws);
  int S = 4;
  while (S > 1 && used + (size_t)S * ((size_t)M * DD * 2 + M * 4) > ws_size) S >>= 1;
  short* po = (short*)cur;
  float* pl = (float*)(po + (size_t)S * M * DD);

  pe_kernel<<<dim3(TT * FF / 256), dim3(256), 0, stream>>>(pe);
  prep_kernel<<<dim3(1), dim3(256), 0, stream>>>(
      w0, b0, bn_a_gamma, bn_a_beta, bn_a_mean, bn_a_var,
      bn1_gamma, bn1_beta, bn1_mean, bn1_var, wd, bd,
      w0pT, b0p, wdpT, bdp);
  proj_kernel<<<dim3(M / 128, 4), dim3(256), 0, stream>>>(
      x, pe, wq, wk, wv, w1, b1, q, k, vt, o2);
  attn_kernel<<<dim3(TT / 64, BB, S), dim3(256), 0, stream>>>(
      q, k, vt, po, pl, 16 / S);
  head_kernel<<<dim3(M / 64), dim3(256), 0, stream>>>(
      po, pl, o2, w0pT, b0p, wdpT, bdp, out, S);
}